// Round 17
// baseline (45.272 us; speedup 1.0000x reference)
//
#include <hip/hip_runtime.h>
#include <stdint.h>

// Spatial transformer: batched dense-displacement trilinear warp.
// z-marching ring pipeline, RING=20, 2-step-ahead staging + counted-vmcnt
// barriers (static counts via peeled epilogue steps).
// vol: [B=2, D=128, H=192, W=192, 1] f32
// trf: [B=2, D=128, H=192, W=192, 3] f32 (displacement along z,y,x)
// out: [B=2, D=128, H=192, W=192, 1] f32

#define BD 128
#define BH 192
#define BW 192
#define DHW (BD*BH*BW)
#define NB 2

// xy tile 16x8, block marches 8 z-steps of 4 -> 32 z, 4096 voxels/block
#define TX 16
#define TY 8
#define NTX (BW/TX)                 // 12
#define NTY (BH/TY)                 // 24
#define ZSTEP 4
#define NSTEPB 8
#define BLKZ (ZSTEP*NSTEPB)         // 32
#define NZB (BD/BLKZ)               // 4
#define NBLK (NTX*NTY*NZB*NB)       // 2304 (%8==0)
#define NXCD 8

// staged slab: x 32 [tx-8..tx+23] * y 16 [ty-4..ty+11], one z = 512 floats = 2KB.
// RING = 20 slabs (slot = z % 20) = 40KB -> 4 blocks/CU.
// 2-deep schedule: at step k (ZS=zA+4k, k<=5) stage N_{k+2} = [ZS+12, ZS+15]
// (clamped to <= BD-4; clamp re-stages identical bytes -> benign). Live set at
// step k = W_k [ZS-4, ZS+7] + N_{k+1} (landed) + N_{k+2} (in flight) = 20
// consecutive z -> bijective slots. Stage-k slots == slots of z-20 in
// [ZS-8, ZS-5] (subset of W_{k-1}), reads ordered by barrier k-1.
// r15 BUG FIXED: windows reach z = zA+35 (z-halo crosses the block boundary);
// staging must cover [zA+32, zA+35] (done at k=5), not stop at zA+31.
#define SXW 32
#define SYW 16
#define SLAB (SXW*SYW)              // 512 floats = 128 chunks of 16B
#define RING 20
#define LDSF (RING*SLAB)            // 10240 floats = 40960 B

typedef float f4v __attribute__((ext_vector_type(4)));
typedef float f2v __attribute__((ext_vector_type(2)));

__device__ __forceinline__ int mod20(int z) {
    return (int)((unsigned)z % 20u);   // compiler magic-div
}

// Counted step barriers (T4). Per-step VMEM issue (k<=5):
// [3 trf][2 stage][F fallback -- drained in-branch by compiler][1 store].
// vmcnt retires in issue order; allowing the 6 newest retires everything
// older (in particular N_{k+1}, staged last step) while this step's
// trf/stage/store ride across. Step 6 issues no stage -> allow 4.
#define STEP_BARRIER_V6() do {                                         \
    asm volatile("s_waitcnt vmcnt(6) lgkmcnt(0)" ::: "memory");        \
    __builtin_amdgcn_s_barrier();                                      \
    __builtin_amdgcn_sched_barrier(0);                                 \
} while (0)
#define STEP_BARRIER_V4() do {                                         \
    asm volatile("s_waitcnt vmcnt(4) lgkmcnt(0)" ::: "memory");        \
    __builtin_amdgcn_s_barrier();                                      \
    __builtin_amdgcn_sched_barrier(0);                                 \
} while (0)

__global__ __launch_bounds__(256, 4) void st_warp_kernel(
    const float* __restrict__ vol,
    const float* __restrict__ trf,
    float* __restrict__ out)
{
    __shared__ __align__(16) float lds[LDSF];

    // XCD-chunked swizzle (2304 % 8 == 0 -> bijective)
    const int bid = blockIdx.x;
    const int swz = (bid % NXCD) * (NBLK / NXCD) + bid / NXCD;
    int t = swz;
    const int txi = t % NTX; t /= NTX;
    const int tyi = t % NTY; t /= NTY;
    const int kzb = t % NZB; t /= NZB;
    const int b   = t;
    const int tx = txi*TX, ty = tyi*TY;
    const int zA = kzb * BLKZ;                  // first output z of this block

    const int sx = min(max(tx - 8, 0), BW - SXW);   // multiple of 4 -> 16B aligned
    const int sy = min(max(ty - 4, 0), BH - SYW);

    const int tid = (int)threadIdx.x;
    const float* volb = vol + (size_t)b * DHW;

    // thread owns an x-PAIR per step: x = X0, X0+1; 8x8x4 pairs = 256 threads
    const int xp = tid & 7;
    const int yb = (tid >> 3) & 7;
    const int zb = tid >> 6;                    // 0..3, wave-uniform
    const int Y  = ty + yb;
    const int X0 = tx + xp*2;

    // ---- stage nslab slabs [zfirst, zfirst+nslab) into ring slots (z % 20) ----
    // chunk f: slab f>>7, within-slab s=f&127 (yi=s>>3, c=s&7). 128%64==0 ->
    // a wave's 64-chunk run never straddles a slab -> slot uniform per wave ->
    // LDS dest stays base + lane*16 (linear, required by gload_lds).
    auto stage = [&](int zfirst, int nslab) {
        const int iters = nslab >> 1;           // nslab slabs = nslab/2 iters of 256
        for (int it = 0; it < iters; ++it) {
            const int f  = tid + it*256;
            const int z  = zfirst + (f >> 7);
            const int s  = f & 127;
            const int yi = s >> 3;
            const int c  = s & 7;
            const int slot = mod20(z);
            const float* g = volb + ((size_t)(z*BH + sy + yi))*BW + sx + (c<<2);
            __builtin_amdgcn_global_load_lds(
                (const __attribute__((address_space(1))) void*)g,
                (__attribute__((address_space(3))) void*)&lds[(slot<<9) + (s<<2)],
                16, 0, 0);
        }
    };

    // trf for the pair at (Z=ZS+zb, Y, X0..X0+1): 6 contiguous floats, 3x float2
    const f2v* t2 = (const f2v*)trf;
    auto load_trf = [&](int ZS, f2v& D0, f2v& D1, f2v& D2) {
        const size_t base2 = (((size_t)((b*BD + ZS + zb)*BH + Y))*BW + X0) * 3 / 2;
        D0 = t2[base2 + 0];     // dz0, dy0
        D1 = t2[base2 + 1];     // dx0, dz1
        D2 = t2[base2 + 2];     // dy1, dx1
    };

    // ---- compute one step: 2 voxels at z = ZS + zb from ring-resident slabs ----
    auto compute_vals = [&](int ZS, f2v D0, f2v D1, f2v D2) -> f2v {
        const int Z   = ZS + zb;
        const int wlo = max(0, ZS - 4);
        const int whi = min(BD - 1, ZS + 7);
        const float dzs[2] = {D0.x, D1.y};
        const float dys[2] = {D0.y, D2.x};
        const float dxs[2] = {D1.x, D2.y};
        float res[2];
#pragma unroll
        for (int jj = 0; jj < 2; ++jj) {
            // high-clamp only; low-side out-of-range fails inwin -> fallback
            // clamps integer corners (exact: colliding corners cancel the weight)
            float cz = fminf((float)Z + dzs[jj], (float)(BD-1));
            float cy = fminf((float)Y + dys[jj], (float)(BH-1));
            float cx = fminf((float)(X0+jj) + dxs[jj], (float)(BW-1));
            float fz = floorf(cz), fy = floorf(cy), fx = floorf(cx);
            int z0 = (int)fz, y0 = (int)fy, x0 = (int)fx;
            int z1 = min(z0+1, BD-1);
            int y1 = min(y0+1, BH-1);
            int x1 = min(x0+1, BW-1);
            float wz = cz - fz, wy = cy - fy, wx = cx - fx;
            float v000,v001,v010,v011,v100,v101,v110,v111;
            bool inwin = (x0 >= sx) & (x1 <= sx+SXW-1) & (y0 >= sy) & (y1 <= sy+SYW-1)
                       & (z0 >= wlo) & (z1 <= whi);
            if (inwin) {
                const int xi  = x0 - sx;
                const int xiA = min(xi, SXW-2);     // x==191 edge: read pair, select
                const bool lo = xi < SXW-1;
                const int sl0 = mod20(z0);
                int sl1 = sl0 + 1;
                sl1 = (sl1 == RING) ? 0 : sl1;
                sl1 = (z1 == z0) ? sl0 : sl1;       // z clamped at top edge
                const int yt0 = (y0 - sy) << 5, yt1 = (y1 - sy) << 5;
                const int rA = (sl0<<9) + yt0 + xiA;
                const int rB = (sl0<<9) + yt1 + xiA;
                const int rC = (sl1<<9) + yt0 + xiA;
                const int rD = (sl1<<9) + yt1 + xiA;
                float a00 = lds[rA], b00 = lds[rA+1];
                float a01 = lds[rB], b01 = lds[rB+1];
                float a10 = lds[rC], b10 = lds[rC+1];
                float a11 = lds[rD], b11 = lds[rD+1];
                v000 = lo ? a00 : b00;  v001 = b00;
                v010 = lo ? a01 : b01;  v011 = b01;
                v100 = lo ? a10 : b10;  v101 = b10;
                v110 = lo ? a11 : b11;  v111 = b11;
            } else {
                const int z0c = max(z0, 0), z1c = max(z1, 0);
                const int y0c = max(y0, 0), y1c = max(y1, 0);
                const int x0c = max(x0, 0), x1c = max(x1, 0);
                const float* p00 = volb + ((size_t)z0c*BH + y0c)*BW;
                const float* p01 = volb + ((size_t)z0c*BH + y1c)*BW;
                const float* p10 = volb + ((size_t)z1c*BH + y0c)*BW;
                const float* p11 = volb + ((size_t)z1c*BH + y1c)*BW;
                v000 = p00[x0c]; v001 = p00[x1c];
                v010 = p01[x0c]; v011 = p01[x1c];
                v100 = p10[x0c]; v101 = p10[x1c];
                v110 = p11[x0c]; v111 = p11[x1c];
            }
            float c00 = v000 + wx*(v001-v000);
            float c01 = v010 + wx*(v011-v010);
            float c10 = v100 + wx*(v101-v100);
            float c11 = v110 + wx*(v111-v110);
            float c0  = c00 + wy*(c01-c00);
            float c1  = c10 + wy*(c11-c10);
            res[jj]   = c0 + wz*(c1-c0);
        }
        f2v r = {res[0], res[1]};
        return r;
    };

    auto store_out = [&](int ZS, f2v r) {
        const size_t of2 = (((size_t)((b*BD + ZS + zb)*BH + Y))*BW + X0) / 2;
        __builtin_nontemporal_store(r, &((f2v*)out)[of2]);
    };

    // ---------------- pipeline ----------------
    f2v D0[2], D1[2], D2[2];
    // prologue: W_0 + N_1 = [max(0,zA-4), zA+11] (16 slabs; 12 at zA=0), full drain
    stage(max(0, zA - 4), (zA == 0) ? 12 : 16);
    load_trf(zA, D0[0], D1[0], D2[0]);
    __syncthreads();

    // k = 0..5: uniform body, static VMEM count [3 trf][2 stage][1 store]
#pragma unroll
    for (int k = 0; k < 6; ++k) {
        const int ZS = zA + k*ZSTEP;
        load_trf(ZS + ZSTEP, D0[(k+1)&1], D1[(k+1)&1], D2[(k+1)&1]);
        // stage N_{k+2} = [ZS+12, ZS+15]; at zA=96, k=5 this clamps to a
        // re-stage of [124,127] (identical bytes into live slots: benign).
        stage(min(ZS + 12, BD - 4), 4);
        f2v r = compute_vals(ZS, D0[k&1], D1[k&1], D2[k&1]);
        store_out(ZS, r);
        STEP_BARRIER_V6();
    }
    // k = 6: no stage left (all slabs through min(zA+35, BD-1) staged by k=5)
    {
        const int ZS = zA + 6*ZSTEP;
        load_trf(ZS + ZSTEP, D0[1], D1[1], D2[1]);
        f2v r = compute_vals(ZS, D0[0], D1[0], D2[0]);
        store_out(ZS, r);
        STEP_BARRIER_V4();        // retires k=5's stage (feeds W_7)
    }
    // k = 7: last step, no prefetch, no barrier
    {
        const int ZS = zA + 7*ZSTEP;
        f2v r = compute_vals(ZS, D0[1], D1[1], D2[1]);
        store_out(ZS, r);
    }
}

extern "C" void kernel_launch(void* const* d_in, const int* in_sizes, int n_in,
                              void* d_out, int out_size, void* d_ws, size_t ws_size,
                              hipStream_t stream) {
    const float* vol = (const float*)d_in[0];
    const float* trf = (const float*)d_in[1];
    float* out = (float*)d_out;

    st_warp_kernel<<<dim3(NBLK), dim3(256), 0, stream>>>(vol, trf, out);
}